// Round 1
// baseline (184.753 us; speedup 1.0000x reference)
//
#include <hip/hip_runtime.h>
#include <math.h>

// Problem constants (from reference):
// N=65536 nodes, F=256 feat, E=16 experts, D=256 emb, H=512 hidden, G=256 graphs
#define NN 65536
#define FF 256
#define EE 16
#define DD 256
#define HH 512
#define GG 256

// Algebraic fold: the hidden activation h is only ever observed through
// z = h @ W_out (2 columns). Therefore
//   z[g] = xm[n] @ (W_emb[e] @ Wtmp) + b_emb[e] @ Wtmp + b_hid @ W_out + b_out,
//   Wtmp = W_hid @ W_out  ([D,2]).
// Kernel 1 precomputes fold[e] = W_emb[e] @ Wtmp ([E,F,2], 4 MFLOP, reads
// W_emb exactly once) and bfold[e] ([E,2], all biases folded). Kernel 2 then
// does, per graph, a single 256-length dot against 2 KB of folded weights,
// plus softmax/loss, plus the deterministic in-block loss sum.
//
// vs. previous version: eliminates the per-graph 256 KB W_emb read (64 MB ->
// 4 MB once) and the per-graph 512 KB W_hid read (128 MB L2 traffic -> 32 MB
// for 64 redundant Wtmp computations), and drops the third launch.

__global__ __launch_bounds__(256) void fold_kernel(
    const float* __restrict__ W_emb,   // [E,F,D]
    const float* __restrict__ b_emb,   // [E,D]
    const float* __restrict__ W_hid,   // [D,H]
    const float* __restrict__ b_hid,   // [H]
    const float* __restrict__ W_out,   // [H,2]
    const float* __restrict__ b_out,   // [2]
    float* __restrict__ fold,          // [E,F,2]
    float* __restrict__ bfold)         // [E,2]
{
    __shared__ __align__(16) float wo[2 * HH];    // W_out staged: wo[2h+j]
    __shared__ __align__(16) float wtmp[2 * DD];  // (W_hid@W_out): wtmp[2d+j]

    const int t = threadIdx.x;
    const int e = blockIdx.x >> 2;   // expert 0..15
    const int r = blockIdx.x & 3;    // row group 0..3 (64 F-rows each)

    // ---- stage W_out into LDS (1024 floats, 4/thread, coalesced) ----
    *(float4*)(wo + 4 * t) = *(const float4*)(W_out + 4 * t);
    __syncthreads();

    // ---- wtmp[t][j] = sum_h W_hid[t][h] * W_out[h][j]  (thread t owns row t)
    // wo[] reads are wave-uniform per iteration -> LDS broadcast, no conflicts.
    {
        const float* __restrict__ Wr = W_hid + (size_t)t * HH;
        float a0 = 0.f, a1 = 0.f;
        #pragma unroll 8
        for (int i = 0; i < HH / 4; ++i) {
            const float4 wh = *(const float4*)(Wr + 4 * i);
            const float4 o0 = *(const float4*)(wo + 8 * i);
            const float4 o1 = *(const float4*)(wo + 8 * i + 4);
            a0 = fmaf(wh.x, o0.x, a0);  a1 = fmaf(wh.x, o0.y, a1);
            a0 = fmaf(wh.y, o0.z, a0);  a1 = fmaf(wh.y, o0.w, a1);
            a0 = fmaf(wh.z, o1.x, a0);  a1 = fmaf(wh.z, o1.y, a1);
            a0 = fmaf(wh.w, o1.z, a0);  a1 = fmaf(wh.w, o1.w, a1);
        }
        wtmp[2 * t]     = a0;
        wtmp[2 * t + 1] = a1;
    }
    __syncthreads();

    // ---- fold[e][row][j] = sum_d W_emb[e][row][d] * wtmp[d][j] ----
    // 4 threads per row, each reducing a 64-wide d segment; float4 loads.
    {
        const int row = (r << 6) + (t >> 2);
        const int d0  = (t & 3) << 6;
        const float* __restrict__ We =
            W_emb + ((size_t)e * FF + row) * DD + d0;
        float z0 = 0.f, z1 = 0.f;
        #pragma unroll 4
        for (int i = 0; i < 16; ++i) {
            const float4 wv = *(const float4*)(We + 4 * i);
            const int d2 = 2 * (d0 + 4 * i);
            z0 = fmaf(wv.x, wtmp[d2 + 0], z0);  z1 = fmaf(wv.x, wtmp[d2 + 1], z1);
            z0 = fmaf(wv.y, wtmp[d2 + 2], z0);  z1 = fmaf(wv.y, wtmp[d2 + 3], z1);
            z0 = fmaf(wv.z, wtmp[d2 + 4], z0);  z1 = fmaf(wv.z, wtmp[d2 + 5], z1);
            z0 = fmaf(wv.w, wtmp[d2 + 6], z0);  z1 = fmaf(wv.w, wtmp[d2 + 7], z1);
        }
        z0 += __shfl_xor(z0, 1, 64);  z1 += __shfl_xor(z1, 1, 64);
        z0 += __shfl_xor(z0, 2, 64);  z1 += __shfl_xor(z1, 2, 64);
        if ((t & 3) == 0)
            *(float2*)(fold + ((size_t)e * FF + row) * 2) = (float2){z0, z1};
    }

    // ---- bfold[e][j] = b_emb[e]@wtmp + b_hid@W_out + b_out  (wave 0 of r==0)
    if (r == 0 && t < 64) {
        float c0 = 0.f, c1 = 0.f;
        // h = 8t .. 8t+7
        const float4 bh0 = *(const float4*)(b_hid + 8 * t);
        const float4 bh1 = *(const float4*)(b_hid + 8 * t + 4);
        const int h2 = 16 * t;
        c0 = fmaf(bh0.x, wo[h2 +  0], c0);  c1 = fmaf(bh0.x, wo[h2 +  1], c1);
        c0 = fmaf(bh0.y, wo[h2 +  2], c0);  c1 = fmaf(bh0.y, wo[h2 +  3], c1);
        c0 = fmaf(bh0.z, wo[h2 +  4], c0);  c1 = fmaf(bh0.z, wo[h2 +  5], c1);
        c0 = fmaf(bh0.w, wo[h2 +  6], c0);  c1 = fmaf(bh0.w, wo[h2 +  7], c1);
        c0 = fmaf(bh1.x, wo[h2 +  8], c0);  c1 = fmaf(bh1.x, wo[h2 +  9], c1);
        c0 = fmaf(bh1.y, wo[h2 + 10], c0);  c1 = fmaf(bh1.y, wo[h2 + 11], c1);
        c0 = fmaf(bh1.z, wo[h2 + 12], c0);  c1 = fmaf(bh1.z, wo[h2 + 13], c1);
        c0 = fmaf(bh1.w, wo[h2 + 14], c0);  c1 = fmaf(bh1.w, wo[h2 + 15], c1);
        // d = 4t .. 4t+3
        const float4 be = *(const float4*)(b_emb + e * DD + 4 * t);
        const int d2 = 8 * t;
        c0 = fmaf(be.x, wtmp[d2 + 0], c0);  c1 = fmaf(be.x, wtmp[d2 + 1], c1);
        c0 = fmaf(be.y, wtmp[d2 + 2], c0);  c1 = fmaf(be.y, wtmp[d2 + 3], c1);
        c0 = fmaf(be.z, wtmp[d2 + 4], c0);  c1 = fmaf(be.z, wtmp[d2 + 5], c1);
        c0 = fmaf(be.w, wtmp[d2 + 6], c0);  c1 = fmaf(be.w, wtmp[d2 + 7], c1);
        for (int off = 32; off; off >>= 1) {
            c0 += __shfl_down(c0, off, 64);
            c1 += __shfl_down(c1, off, 64);
        }
        if (t == 0) {
            bfold[2 * e + 0] = c0 + b_out[0];
            bfold[2 * e + 1] = c1 + b_out[1];
        }
    }
}

// One block, 16 waves. Each wave handles 16 graphs (one per pass):
// z_j = sum_f xm[n][f] * fold[e][f][j] + bfold[e][j]; lane l covers f=4l..4l+3
// so the whole reduction is one pass + 6 shuffle steps. The deterministic
// loss sum over all 256 graphs happens in-block (no third launch).
__global__ __launch_bounds__(1024) void graph_loss_kernel(
    const float* __restrict__ node_fea,   // [N,F]
    const float* __restrict__ masks,      // [N,F]
    const int*   __restrict__ node_type,  // [N]
    const int*   __restrict__ g_node_id,  // [G]
    const int*   __restrict__ label,      // [G]
    const float* __restrict__ fold,       // [E,F,2]
    const float* __restrict__ bfold,      // [E,2]
    float* __restrict__ out)              // [2G probs][1 loss]
{
    __shared__ float lterm[GG];
    const int t = threadIdx.x;
    const int w = t >> 6;   // wave 0..15
    const int l = t & 63;

    #pragma unroll
    for (int p = 0; p < GG / 16; ++p) {
        const int g = (p << 4) + w;
        const int n = g_node_id[g];      // wave-uniform -> scalar loads
        const int e = node_type[n];
        const size_t nb = (size_t)n * FF + (l << 2);
        const float4 x = *(const float4*)(node_fea + nb);
        const float4 m = *(const float4*)(masks + nb);
        const float* fr = fold + e * (FF * 2) + (l << 3);
        const float4 wa = *(const float4*)(fr);
        const float4 wb = *(const float4*)(fr + 4);
        const float x0 = x.x * m.x, x1 = x.y * m.y;
        const float x2 = x.z * m.z, x3 = x.w * m.w;
        float z0 = x0 * wa.x + x1 * wa.z + x2 * wb.x + x3 * wb.z;
        float z1 = x0 * wa.y + x1 * wa.w + x2 * wb.y + x3 * wb.w;
        for (int off = 32; off; off >>= 1) {
            z0 += __shfl_down(z0, off, 64);
            z1 += __shfl_down(z1, off, 64);
        }
        if (l == 0) {
            z0 += bfold[2 * e + 0];
            z1 += bfold[2 * e + 1];
            // probs = softmax(z)
            const float mz = fmaxf(z0, z1);
            const float e0 = expf(z0 - mz), e1 = expf(z1 - mz);
            const float inv = 1.0f / (e0 + e1);
            const float p0 = e0 * inv, p1 = e1 * inv;
            out[2 * g + 0] = p0;
            out[2 * g + 1] = p1;
            // loss term = lse(probs) - probs[label]
            const float mp  = fmaxf(p0, p1);
            const float lse = mp + logf(expf(p0 - mp) + expf(p1 - mp));
            lterm[g] = lse - ((label[g] == 0) ? p0 : p1);
        }
    }
    __syncthreads();

    if (t < 64) {
        float v = lterm[t] + lterm[t + 64] + lterm[t + 128] + lterm[t + 192];
        for (int off = 32; off; off >>= 1) v += __shfl_down(v, off, 64);
        if (t == 0) out[2 * GG] = v;
    }
}

extern "C" void kernel_launch(void* const* d_in, const int* in_sizes, int n_in,
                              void* d_out, int out_size, void* d_ws, size_t ws_size,
                              hipStream_t stream) {
    const float* node_fea  = (const float*)d_in[0];
    const float* masks     = (const float*)d_in[1];
    const int*   node_type = (const int*)  d_in[2];
    const int*   g_node_id = (const int*)  d_in[3];
    const int*   label     = (const int*)  d_in[4];
    const float* W_emb     = (const float*)d_in[5];
    const float* b_emb     = (const float*)d_in[6];
    const float* W_hid     = (const float*)d_in[7];
    const float* b_hid     = (const float*)d_in[8];
    const float* W_out     = (const float*)d_in[9];
    const float* b_out     = (const float*)d_in[10];

    float* out   = (float*)d_out;          // [G*2 probs][1 loss] = 513 floats
    float* fold  = (float*)d_ws;           // [E*F*2] = 8192 floats
    float* bfold = fold + EE * FF * 2;     // [E*2]   = 32 floats

    fold_kernel<<<EE * 4, 256, 0, stream>>>(
        W_emb, b_emb, W_hid, b_hid, W_out, b_out, fold, bfold);

    graph_loss_kernel<<<1, 1024, 0, stream>>>(
        node_fea, masks, node_type, g_node_id, label, fold, bfold, out);
}

// Round 2
// 158.352 us; speedup vs baseline: 1.1667x; 1.1667x over previous
//
#include <hip/hip_runtime.h>
#include <math.h>

// Problem constants (from reference):
// N=65536 nodes, F=256 feat, E=16 experts, D=256 emb, H=512 hidden, G=256 graphs
#define NN 65536
#define FF 256
#define EE 16
#define DD 256
#define HH 512
#define GG 256

// Algebraic fold (round-1, verified): h is only observed through z = h @ W_out
// (2 columns), so
//   z[g] = xm[n] @ fold[e] + bfold[e],
//   fold[e] = W_emb[e] @ (W_hid @ W_out)   [E,F,2]
//   bfold[e] = b_emb[e] @ (W_hid@W_out) + b_hid@W_out + b_out   [E,2]
// Per-graph work collapses to a 256-length dot against 2 KB of folded weights.
//
// Round-1 post-mortem: the fold was right but the graph stage ran on ONE block
// (one CU) with 16 serial passes/wave -> ~40 us of unhidden scattered-HBM
// latency (+35 us regression). This round spreads graphs over 64 blocks
// (1 wave = 1 graph, single pass) and restores the tiny deterministic
// loss-reduce launch.

__global__ __launch_bounds__(256) void fold_kernel(
    const float* __restrict__ W_emb,   // [E,F,D]
    const float* __restrict__ b_emb,   // [E,D]
    const float* __restrict__ W_hid,   // [D,H]
    const float* __restrict__ b_hid,   // [H]
    const float* __restrict__ W_out,   // [H,2]
    const float* __restrict__ b_out,   // [2]
    float* __restrict__ fold,          // [E,F,2]
    float* __restrict__ bfold)         // [E,2]
{
    __shared__ __align__(16) float wo[2 * HH];    // W_out staged: wo[2h+j]
    __shared__ __align__(16) float wtmp[2 * DD];  // (W_hid@W_out): wtmp[2d+j]

    const int t = threadIdx.x;
    const int e = blockIdx.x >> 2;   // expert 0..15
    const int r = blockIdx.x & 3;    // row group 0..3 (64 F-rows each)

    // ---- stage W_out into LDS (1024 floats, 4/thread, coalesced) ----
    *(float4*)(wo + 4 * t) = *(const float4*)(W_out + 4 * t);
    __syncthreads();

    // ---- wtmp[t][j] = sum_h W_hid[t][h] * W_out[h][j]  (thread t owns row t)
    // wo[] reads are wave-uniform per iteration -> LDS broadcast, no conflicts.
    {
        const float* __restrict__ Wr = W_hid + (size_t)t * HH;
        float a0 = 0.f, a1 = 0.f;
        #pragma unroll 8
        for (int i = 0; i < HH / 4; ++i) {
            const float4 wh = *(const float4*)(Wr + 4 * i);
            const float4 o0 = *(const float4*)(wo + 8 * i);
            const float4 o1 = *(const float4*)(wo + 8 * i + 4);
            a0 = fmaf(wh.x, o0.x, a0);  a1 = fmaf(wh.x, o0.y, a1);
            a0 = fmaf(wh.y, o0.z, a0);  a1 = fmaf(wh.y, o0.w, a1);
            a0 = fmaf(wh.z, o1.x, a0);  a1 = fmaf(wh.z, o1.y, a1);
            a0 = fmaf(wh.w, o1.z, a0);  a1 = fmaf(wh.w, o1.w, a1);
        }
        wtmp[2 * t]     = a0;
        wtmp[2 * t + 1] = a1;
    }
    __syncthreads();

    // ---- fold[e][row][j] = sum_d W_emb[e][row][d] * wtmp[d][j] ----
    // 4 threads per row, each reducing a 64-wide d segment; float4 loads.
    {
        const int row = (r << 6) + (t >> 2);
        const int d0  = (t & 3) << 6;
        const float* __restrict__ We =
            W_emb + ((size_t)e * FF + row) * DD + d0;
        float z0 = 0.f, z1 = 0.f;
        #pragma unroll 4
        for (int i = 0; i < 16; ++i) {
            const float4 wv = *(const float4*)(We + 4 * i);
            const int d2 = 2 * (d0 + 4 * i);
            z0 = fmaf(wv.x, wtmp[d2 + 0], z0);  z1 = fmaf(wv.x, wtmp[d2 + 1], z1);
            z0 = fmaf(wv.y, wtmp[d2 + 2], z0);  z1 = fmaf(wv.y, wtmp[d2 + 3], z1);
            z0 = fmaf(wv.z, wtmp[d2 + 4], z0);  z1 = fmaf(wv.z, wtmp[d2 + 5], z1);
            z0 = fmaf(wv.w, wtmp[d2 + 6], z0);  z1 = fmaf(wv.w, wtmp[d2 + 7], z1);
        }
        z0 += __shfl_xor(z0, 1, 64);  z1 += __shfl_xor(z1, 1, 64);
        z0 += __shfl_xor(z0, 2, 64);  z1 += __shfl_xor(z1, 2, 64);
        if ((t & 3) == 0)
            *(float2*)(fold + ((size_t)e * FF + row) * 2) = (float2){z0, z1};
    }

    // ---- bfold[e][j] = b_emb[e]@wtmp + b_hid@W_out + b_out  (wave 0 of r==0)
    if (r == 0 && t < 64) {
        float c0 = 0.f, c1 = 0.f;
        // h = 8t .. 8t+7
        const float4 bh0 = *(const float4*)(b_hid + 8 * t);
        const float4 bh1 = *(const float4*)(b_hid + 8 * t + 4);
        const int h2 = 16 * t;
        c0 = fmaf(bh0.x, wo[h2 +  0], c0);  c1 = fmaf(bh0.x, wo[h2 +  1], c1);
        c0 = fmaf(bh0.y, wo[h2 +  2], c0);  c1 = fmaf(bh0.y, wo[h2 +  3], c1);
        c0 = fmaf(bh0.z, wo[h2 +  4], c0);  c1 = fmaf(bh0.z, wo[h2 +  5], c1);
        c0 = fmaf(bh0.w, wo[h2 +  6], c0);  c1 = fmaf(bh0.w, wo[h2 +  7], c1);
        c0 = fmaf(bh1.x, wo[h2 +  8], c0);  c1 = fmaf(bh1.x, wo[h2 +  9], c1);
        c0 = fmaf(bh1.y, wo[h2 + 10], c0);  c1 = fmaf(bh1.y, wo[h2 + 11], c1);
        c0 = fmaf(bh1.z, wo[h2 + 12], c0);  c1 = fmaf(bh1.z, wo[h2 + 13], c1);
        c0 = fmaf(bh1.w, wo[h2 + 14], c0);  c1 = fmaf(bh1.w, wo[h2 + 15], c1);
        // d = 4t .. 4t+3
        const float4 be = *(const float4*)(b_emb + e * DD + 4 * t);
        const int d2 = 8 * t;
        c0 = fmaf(be.x, wtmp[d2 + 0], c0);  c1 = fmaf(be.x, wtmp[d2 + 1], c1);
        c0 = fmaf(be.y, wtmp[d2 + 2], c0);  c1 = fmaf(be.y, wtmp[d2 + 3], c1);
        c0 = fmaf(be.z, wtmp[d2 + 4], c0);  c1 = fmaf(be.z, wtmp[d2 + 5], c1);
        c0 = fmaf(be.w, wtmp[d2 + 6], c0);  c1 = fmaf(be.w, wtmp[d2 + 7], c1);
        for (int off = 32; off; off >>= 1) {
            c0 += __shfl_down(c0, off, 64);
            c1 += __shfl_down(c1, off, 64);
        }
        if (t == 0) {
            bfold[2 * e + 0] = c0 + b_out[0];
            bfold[2 * e + 1] = c1 + b_out[1];
        }
    }
}

// 64 blocks x 4 waves; one wave per graph, single pass:
// z_j = sum_f xm[n][f] * fold[e][f][j] + bfold[e][j]; lane l covers f=4l..4l+3
// -> one scattered 32 B node read + 32 B L2-resident fold read per lane,
// then a 6-step shuffle reduce. 64 blocks spread across CUs hide the
// gather latency that round-1's single block could not.
__global__ __launch_bounds__(256) void graph_kernel(
    const float* __restrict__ node_fea,   // [N,F]
    const float* __restrict__ masks,      // [N,F]
    const int*   __restrict__ node_type,  // [N]
    const int*   __restrict__ g_node_id,  // [G]
    const int*   __restrict__ label,      // [G]
    const float* __restrict__ fold,       // [E,F,2]
    const float* __restrict__ bfold,      // [E,2]
    float* __restrict__ probs_out,        // [G,2]
    float* __restrict__ lterm)            // [G] workspace
{
    const int t = threadIdx.x;
    const int w = t >> 6;   // wave 0..3
    const int l = t & 63;
    const int g = (blockIdx.x << 2) + w;

    const int n = g_node_id[g];      // wave-uniform -> scalar loads
    const int e = node_type[n];
    const size_t nb = (size_t)n * FF + (l << 2);
    const float4 x = *(const float4*)(node_fea + nb);
    const float4 m = *(const float4*)(masks + nb);
    const float* fr = fold + e * (FF * 2) + (l << 3);
    const float4 wa = *(const float4*)(fr);
    const float4 wb = *(const float4*)(fr + 4);
    const float x0 = x.x * m.x, x1 = x.y * m.y;
    const float x2 = x.z * m.z, x3 = x.w * m.w;
    float z0 = x0 * wa.x + x1 * wa.z + x2 * wb.x + x3 * wb.z;
    float z1 = x0 * wa.y + x1 * wa.w + x2 * wb.y + x3 * wb.w;
    for (int off = 32; off; off >>= 1) {
        z0 += __shfl_down(z0, off, 64);
        z1 += __shfl_down(z1, off, 64);
    }
    if (l == 0) {
        z0 += bfold[2 * e + 0];
        z1 += bfold[2 * e + 1];
        // probs = softmax(z)
        const float mz = fmaxf(z0, z1);
        const float e0 = expf(z0 - mz), e1 = expf(z1 - mz);
        const float inv = 1.0f / (e0 + e1);
        const float p0 = e0 * inv, p1 = e1 * inv;
        probs_out[2 * g + 0] = p0;
        probs_out[2 * g + 1] = p1;
        // loss term = -(log_softmax(probs)[label]) = lse(probs) - probs[label]
        const float mp  = fmaxf(p0, p1);
        const float lse = mp + logf(expf(p0 - mp) + expf(p1 - mp));
        lterm[g] = lse - ((label[g] == 0) ? p0 : p1);
    }
}

// Deterministic single-block sum of the 256 per-graph loss terms.
__global__ __launch_bounds__(256) void loss_reduce_kernel(
    const float* __restrict__ lterm, float* __restrict__ out)
{
    __shared__ float red[4];
    int t = threadIdx.x;
    float v = lterm[t];
    for (int off = 32; off; off >>= 1) v += __shfl_down(v, off, 64);
    if ((t & 63) == 0) red[t >> 6] = v;
    __syncthreads();
    if (t == 0) out[0] = red[0] + red[1] + red[2] + red[3];
}

extern "C" void kernel_launch(void* const* d_in, const int* in_sizes, int n_in,
                              void* d_out, int out_size, void* d_ws, size_t ws_size,
                              hipStream_t stream) {
    const float* node_fea  = (const float*)d_in[0];
    const float* masks     = (const float*)d_in[1];
    const int*   node_type = (const int*)  d_in[2];
    const int*   g_node_id = (const int*)  d_in[3];
    const int*   label     = (const int*)  d_in[4];
    const float* W_emb     = (const float*)d_in[5];
    const float* b_emb     = (const float*)d_in[6];
    const float* W_hid     = (const float*)d_in[7];
    const float* b_hid     = (const float*)d_in[8];
    const float* W_out     = (const float*)d_in[9];
    const float* b_out     = (const float*)d_in[10];

    float* out   = (float*)d_out;          // [G*2 probs][1 loss] = 513 floats
    float* fold  = (float*)d_ws;           // [E*F*2] = 8192 floats
    float* bfold = fold + EE * FF * 2;     // [E*2]   = 32 floats
    float* lterm = bfold + EE * 2;         // [G]     = 256 floats

    fold_kernel<<<EE * 4, 256, 0, stream>>>(
        W_emb, b_emb, W_hid, b_hid, W_out, b_out, fold, bfold);

    graph_kernel<<<GG / 4, 256, 0, stream>>>(
        node_fea, masks, node_type, g_node_id, label, fold, bfold,
        out, lterm);

    loss_reduce_kernel<<<1, 256, 0, stream>>>(lterm, out + GG * 2);
}

// Round 3
// 156.381 us; speedup vs baseline: 1.1814x; 1.0126x over previous
//
#include <hip/hip_runtime.h>
#include <math.h>

// Problem constants (from reference):
// N=65536 nodes, F=256 feat, E=16 experts, D=256 emb, H=512 hidden, G=256 graphs
#define NN 65536
#define FF 256
#define EE 16
#define DD 256
#define HH 512
#define GG 256
#define NBLK 64

// Algebraic fold (verified rounds 1-2): h is only observed through z = h@W_out
// (2 cols), so  z[g] = xm[n] @ fold[e] + b_emb[e] @ wtmp + (b_hid@W_out + b_out)
// with wtmp = W_hid @ W_out ([D,2]) and fold[e] = W_emb[e] @ wtmp ([E,F,2]).
//
// Round-2 post-mortem: fold algebra right, but 3 launches + every fold block
// redundantly streaming the 512 KB W_hid (32 MB L2 for a 2 KB result) cost
// ~9 us vs round 0. This round: ONE kernel, 64 co-resident blocks, device-scope
// grid barriers (G16 pattern), wtmp distributed 4 rows/block (8 KB W_hid each),
// node-gather prefetched into registers under phase-1 compute, loss summed
// in-kernel. Launch prologue: one 16 B hipMemsetAsync to zero the counters.
//
// ws layout: [0..15 B] 4 barrier ints (memset 0 each launch)
//   floats: wtmp @ 16..527, bconst @ 528..529, lterm @ 544..799,
//           fold @ 1024..9215  ([e][f][2])

__device__ __forceinline__ void grid_barrier(int* c, int target) {
    __syncthreads();
    if (threadIdx.x == 0) {
        __hip_atomic_fetch_add(c, 1, __ATOMIC_ACQ_REL, __HIP_MEMORY_SCOPE_AGENT);
        while (__hip_atomic_load(c, __ATOMIC_ACQUIRE, __HIP_MEMORY_SCOPE_AGENT)
               < target) {
            __builtin_amdgcn_s_sleep(1);
        }
    }
    __syncthreads();
}

__global__ __launch_bounds__(256) void fused_all_kernel(
    const float* __restrict__ node_fea,   // [N,F]
    const float* __restrict__ masks,      // [N,F]
    const int*   __restrict__ node_type,  // [N]
    const int*   __restrict__ g_node_id,  // [G]
    const int*   __restrict__ label,      // [G]
    const float* __restrict__ W_emb,      // [E,F,D]
    const float* __restrict__ b_emb,      // [E,D]
    const float* __restrict__ W_hid,      // [D,H]
    const float* __restrict__ b_hid,      // [H]
    const float* __restrict__ W_out,      // [H,2]
    const float* __restrict__ b_out,      // [2]
    float* __restrict__ out,              // [2G probs][1 loss]
    float* __restrict__ ws_f,
    int*   __restrict__ ws_i)
{
    __shared__ __align__(16) float lwtmp[2 * DD];

    const int t = threadIdx.x;
    const int b = blockIdx.x;
    const int w = t >> 6;   // wave 0..3
    const int l = t & 63;

    float* wtmp   = ws_f + 16;    // [D][2]
    float* bconst = ws_f + 528;   // [2]
    float* lterm  = ws_f + 544;   // [G]
    float* fold   = ws_f + 1024;  // [E][F][2]

    // ---- phase 1a: prefetch this wave's graph data into registers ----
    // (scattered HBM latency hides under phase-1b compute)
    const int g = (b << 2) + w;          // 64 blocks x 4 waves = 256 graphs
    const int n = g_node_id[g];          // wave-uniform -> scalar loads
    const int e = node_type[n];
    const size_t nb = (size_t)n * FF + (l << 2);
    const float4 x4  = *(const float4*)(node_fea + nb);
    const float4 m4  = *(const float4*)(masks + nb);
    const float4 be4 = *(const float4*)(b_emb + e * DD + (l << 2));

    // ---- phase 1b: wtmp row d = 4b+w  (8 KB of W_hid per block, no redundancy)
    {
        const int d = (b << 2) + w;      // covers 0..255
        const float* Wr = W_hid + (size_t)d * HH + (l << 3);  // 8 h's per lane
        const float4 h0 = *(const float4*)(Wr);
        const float4 h1 = *(const float4*)(Wr + 4);
        const float* Wo = W_out + (l << 4);                   // rows 8l..8l+7
        const float4 o0 = *(const float4*)(Wo);
        const float4 o1 = *(const float4*)(Wo + 4);
        const float4 o2 = *(const float4*)(Wo + 8);
        const float4 o3 = *(const float4*)(Wo + 12);
        float a0 = h0.x*o0.x + h0.y*o0.z + h0.z*o1.x + h0.w*o1.z
                 + h1.x*o2.x + h1.y*o2.z + h1.z*o3.x + h1.w*o3.z;
        float a1 = h0.x*o0.y + h0.y*o0.w + h0.z*o1.y + h0.w*o1.w
                 + h1.x*o2.y + h1.y*o2.w + h1.z*o3.y + h1.w*o3.w;
        // b_hid @ W_out (+b_out) piggybacks on block 0 / wave 0 (reuses o0..o3)
        float c0 = 0.f, c1 = 0.f;
        if (b == 0 && w == 0) {
            const float4 bh0 = *(const float4*)(b_hid + (l << 3));
            const float4 bh1 = *(const float4*)(b_hid + (l << 3) + 4);
            c0 = bh0.x*o0.x + bh0.y*o0.z + bh0.z*o1.x + bh0.w*o1.z
               + bh1.x*o2.x + bh1.y*o2.z + bh1.z*o3.x + bh1.w*o3.z;
            c1 = bh0.x*o0.y + bh0.y*o0.w + bh0.z*o1.y + bh0.w*o1.w
               + bh1.x*o2.y + bh1.y*o2.w + bh1.z*o3.y + bh1.w*o3.w;
        }
        for (int off = 32; off; off >>= 1) {
            a0 += __shfl_down(a0, off, 64);
            a1 += __shfl_down(a1, off, 64);
            c0 += __shfl_down(c0, off, 64);
            c1 += __shfl_down(c1, off, 64);
        }
        if (l == 0) {
            wtmp[2 * d]     = a0;
            wtmp[2 * d + 1] = a1;
            if (b == 0 && w == 0) {
                bconst[0] = c0 + b_out[0];
                bconst[1] = c1 + b_out[1];
            }
        }
    }
    grid_barrier(ws_i + 0, NBLK);

    // ---- phase 2: fold[e2][row][j] = sum_d W_emb[e2][row][d] * wtmp[d][j] ----
    {
        // stage wtmp into LDS (coalesced float2 per thread)
        *(float2*)(lwtmp + 2 * t) = *(const float2*)(wtmp + 2 * t);
        __syncthreads();

        const int e2  = b >> 2;              // expert 0..15
        const int r   = b & 3;               // row group
        const int row = (r << 6) + (t >> 2); // 4 threads per row
        const int d0  = (t & 3) << 6;
        const float* We = W_emb + ((size_t)e2 * FF + row) * DD + d0;
        float z0 = 0.f, z1 = 0.f;
        #pragma unroll 4
        for (int i = 0; i < 16; ++i) {
            const float4 wv = *(const float4*)(We + 4 * i);
            const int d2 = 2 * (d0 + 4 * i);
            z0 = fmaf(wv.x, lwtmp[d2 + 0], z0);  z1 = fmaf(wv.x, lwtmp[d2 + 1], z1);
            z0 = fmaf(wv.y, lwtmp[d2 + 2], z0);  z1 = fmaf(wv.y, lwtmp[d2 + 3], z1);
            z0 = fmaf(wv.z, lwtmp[d2 + 4], z0);  z1 = fmaf(wv.z, lwtmp[d2 + 5], z1);
            z0 = fmaf(wv.w, lwtmp[d2 + 6], z0);  z1 = fmaf(wv.w, lwtmp[d2 + 7], z1);
        }
        z0 += __shfl_xor(z0, 1, 64);  z1 += __shfl_xor(z1, 1, 64);
        z0 += __shfl_xor(z0, 2, 64);  z1 += __shfl_xor(z1, 2, 64);
        if ((t & 3) == 0)
            *(float2*)(fold + ((size_t)e2 * FF + row) * 2) = (float2){z0, z1};
    }
    grid_barrier(ws_i + 1, NBLK);

    // ---- phase 3: z = xm @ fold[e] + b_emb[e] @ wtmp + bconst; softmax; loss --
    {
        const float* fr = fold + e * (FF * 2) + (l << 3);
        const float4 wa  = *(const float4*)(fr);
        const float4 wb  = *(const float4*)(fr + 4);
        const float4 wt0 = *(const float4*)(wtmp + (l << 3));
        const float4 wt1 = *(const float4*)(wtmp + (l << 3) + 4);
        const float x0 = x4.x * m4.x, x1 = x4.y * m4.y;
        const float x2 = x4.z * m4.z, x3 = x4.w * m4.w;
        float z0 = x0*wa.x + x1*wa.z + x2*wb.x + x3*wb.z
                 + be4.x*wt0.x + be4.y*wt0.z + be4.z*wt1.x + be4.w*wt1.z;
        float z1 = x0*wa.y + x1*wa.w + x2*wb.y + x3*wb.w
                 + be4.x*wt0.y + be4.y*wt0.w + be4.z*wt1.y + be4.w*wt1.w;
        for (int off = 32; off; off >>= 1) {
            z0 += __shfl_down(z0, off, 64);
            z1 += __shfl_down(z1, off, 64);
        }
        if (l == 0) {
            z0 += bconst[0];
            z1 += bconst[1];
            const float mz = fmaxf(z0, z1);
            const float e0 = expf(z0 - mz), e1 = expf(z1 - mz);
            const float inv = 1.0f / (e0 + e1);
            const float p0 = e0 * inv, p1 = e1 * inv;
            out[2 * g + 0] = p0;
            out[2 * g + 1] = p1;
            // loss term = -(log_softmax(probs)[label]) = lse(probs) - probs[label]
            const float mp  = fmaxf(p0, p1);
            const float lse = mp + logf(expf(p0 - mp) + expf(p1 - mp));
            lterm[g] = lse - ((label[g] == 0) ? p0 : p1);
        }
    }
    grid_barrier(ws_i + 2, NBLK);

    // ---- phase 4: deterministic loss sum (block 0, fixed order) ----
    if (b == 0 && t < 64) {
        float v = lterm[t] + lterm[t + 64] + lterm[t + 128] + lterm[t + 192];
        for (int off = 32; off; off >>= 1) v += __shfl_down(v, off, 64);
        if (t == 0) out[2 * GG] = v;
    }
}

extern "C" void kernel_launch(void* const* d_in, const int* in_sizes, int n_in,
                              void* d_out, int out_size, void* d_ws, size_t ws_size,
                              hipStream_t stream) {
    const float* node_fea  = (const float*)d_in[0];
    const float* masks     = (const float*)d_in[1];
    const int*   node_type = (const int*)  d_in[2];
    const int*   g_node_id = (const int*)  d_in[3];
    const int*   label     = (const int*)  d_in[4];
    const float* W_emb     = (const float*)d_in[5];
    const float* b_emb     = (const float*)d_in[6];
    const float* W_hid     = (const float*)d_in[7];
    const float* b_hid     = (const float*)d_in[8];
    const float* W_out     = (const float*)d_in[9];
    const float* b_out     = (const float*)d_in[10];

    float* out  = (float*)d_out;   // [G*2 probs][1 loss] = 513 floats
    float* ws_f = (float*)d_ws;
    int*   ws_i = (int*)d_ws;      // counters live in bytes [0..15]

    // zero the 3 grid-barrier counters (stream-ordered; graph-capturable)
    hipMemsetAsync(d_ws, 0, 16, stream);

    fused_all_kernel<<<NBLK, 256, 0, stream>>>(
        node_fea, masks, node_type, g_node_id, label,
        W_emb, b_emb, W_hid, b_hid, W_out, b_out,
        out, ws_f, ws_i);
}

// Round 4
// 154.199 us; speedup vs baseline: 1.1981x; 1.0141x over previous
//
#include <hip/hip_runtime.h>
#include <math.h>

// Problem constants (from reference):
// N=65536 nodes, F=256 feat, E=16 experts, D=256 emb, H=512 hidden, G=256 graphs
#define NN 65536
#define FF 256
#define EE 16
#define DD 256
#define HH 512
#define GG 256

// Round-3 post-mortem: grid barriers (~2 us each, cross-XCD atomic spin) and
// extra dispatches cost more than they save; round 0 (2 launches, zero
// cross-block coordination) is still the best point (149.3 us).
//
// This round keeps EXACTLY 2 dispatches and round 0's proven per-graph block
// structure, but applies the minimal fold: only wtmp = W_hid @ W_out ([D,2]).
//  - Launch A (64 blocks): distributed wtmp (8 KB W_hid per block, 512 KB
//    total, read once) + bconst = b_hid@W_out + b_out + zero the done-counter.
//  - Launch B (256 blocks, 1 graph each): round 0's stage 1+2 (xm, emb =
//    xm@W_emb[e] + b_emb[e]), then z = emb @ wtmp (2 KB) instead of the old
//    512 KB W_hid stage -> per-block traffic 768 KB -> 258 KB. Loss summed
//    deterministically by the LAST finishing block (release fence + counter;
//    fixed-order sum) -- no 3rd launch, no spin for 255 blocks.
// W_emb is deliberately NOT folded: its 16x-redundant reads are L2-resident
// and parallel across 256 CUs; folding it costs more in coordination.
//
// ws layout: int counter @ bytes 0..3; floats: wtmp @ [16..527],
// bconst @ [528..529], lterm @ [544..799].

__global__ __launch_bounds__(256) void wtmp_kernel(
    const float* __restrict__ W_hid,   // [D,H]
    const float* __restrict__ b_hid,   // [H]
    const float* __restrict__ W_out,   // [H,2]
    const float* __restrict__ b_out,   // [2]
    float* __restrict__ ws_f,
    int*   __restrict__ ws_i)
{
    const int t = threadIdx.x;
    const int b = blockIdx.x;
    const int w = t >> 6;
    const int l = t & 63;

    float* wtmp   = ws_f + 16;    // [D][2]
    float* bconst = ws_f + 528;   // [2]

    if (b == 0 && t == 0) ws_i[0] = 0;   // reset done-counter for launch B

    // wave (b,w) computes wtmp row d = 4b+w; lane l covers h = 8l..8l+7
    const int d = (b << 2) + w;
    const float* Wr = W_hid + (size_t)d * HH + (l << 3);
    const float4 h0 = *(const float4*)(Wr);
    const float4 h1 = *(const float4*)(Wr + 4);
    const float* Wo = W_out + (l << 4);   // rows 8l..8l+7, 2 floats each
    const float4 o0 = *(const float4*)(Wo);
    const float4 o1 = *(const float4*)(Wo + 4);
    const float4 o2 = *(const float4*)(Wo + 8);
    const float4 o3 = *(const float4*)(Wo + 12);
    float a0 = h0.x*o0.x + h0.y*o0.z + h0.z*o1.x + h0.w*o1.z
             + h1.x*o2.x + h1.y*o2.z + h1.z*o3.x + h1.w*o3.z;
    float a1 = h0.x*o0.y + h0.y*o0.w + h0.z*o1.y + h0.w*o1.w
             + h1.x*o2.y + h1.y*o2.w + h1.z*o3.y + h1.w*o3.w;

    // bconst piggybacks on block 0 wave 0 (reuses o0..o3)
    float c0 = 0.f, c1 = 0.f;
    if (b == 0 && w == 0) {
        const float4 bh0 = *(const float4*)(b_hid + (l << 3));
        const float4 bh1 = *(const float4*)(b_hid + (l << 3) + 4);
        c0 = bh0.x*o0.x + bh0.y*o0.z + bh0.z*o1.x + bh0.w*o1.z
           + bh1.x*o2.x + bh1.y*o2.z + bh1.z*o3.x + bh1.w*o3.z;
        c1 = bh0.x*o0.y + bh0.y*o0.w + bh0.z*o1.y + bh0.w*o1.w
           + bh1.x*o2.y + bh1.y*o2.w + bh1.z*o3.y + bh1.w*o3.w;
    }
    for (int off = 32; off; off >>= 1) {
        a0 += __shfl_down(a0, off, 64);
        a1 += __shfl_down(a1, off, 64);
        c0 += __shfl_down(c0, off, 64);
        c1 += __shfl_down(c1, off, 64);
    }
    if (l == 0) {
        wtmp[2 * d]     = a0;
        wtmp[2 * d + 1] = a1;
        if (b == 0 && w == 0) {
            bconst[0] = c0 + b_out[0];
            bconst[1] = c1 + b_out[1];
        }
    }
}

// One block per graph (round 0's proven structure, minus the W_hid stage).
__global__ __launch_bounds__(256) void graph_kernel(
    const float* __restrict__ node_fea,   // [N,F]
    const float* __restrict__ masks,      // [N,F]
    const int*   __restrict__ node_type,  // [N]
    const int*   __restrict__ g_node_id,  // [G]
    const int*   __restrict__ label,      // [G]
    const float* __restrict__ W_emb,      // [E,F,D]
    const float* __restrict__ b_emb,      // [E,D]
    float* __restrict__ out,              // [2G probs][1 loss]
    float* __restrict__ ws_f,
    int*   __restrict__ ws_i)
{
    __shared__ __align__(16) float xm[FF];
    __shared__ __align__(16) float part[4][DD];
    __shared__ float red0[4];
    __shared__ float red1[4];
    __shared__ int lastflag;

    const int g = blockIdx.x;
    const int t = threadIdx.x;
    const int w = t >> 6;   // wave 0..3
    const int l = t & 63;
    const int c = l << 2;   // lane's 4 d-columns
    const int n = g_node_id[g];
    const int e = node_type[n];

    const float* wtmp   = ws_f + 16;
    const float* bconst = ws_f + 528;
    float*       lterm  = ws_f + 544;

    // ---- stage 1: masked features ----
    {
        const size_t base = (size_t)n * FF + t;
        xm[t] = node_fea[base] * masks[base];
    }
    __syncthreads();

    // ---- stage 2: emb = xm @ W_emb[e]; wave w reduces f in [64w,64w+64) ----
    {
        const float* __restrict__ Wb = W_emb + (size_t)e * FF * DD;
        float4 acc = {0.f, 0.f, 0.f, 0.f};
        #pragma unroll 8
        for (int i = 0; i < 64; ++i) {
            const int f = (w << 6) + i;
            const float s = xm[f];
            const float4 wv = *(const float4*)(Wb + (size_t)f * DD + c);
            acc.x = fmaf(s, wv.x, acc.x);
            acc.y = fmaf(s, wv.y, acc.y);
            acc.z = fmaf(s, wv.z, acc.z);
            acc.w = fmaf(s, wv.w, acc.w);
        }
        *(float4*)&part[w][c] = acc;
    }
    __syncthreads();

    // ---- stage 3: thread t owns d=t; z = emb @ wtmp ----
    float z0p, z1p;
    {
        const float embt = part[0][t] + part[1][t] + part[2][t] + part[3][t]
                         + b_emb[e * DD + t];
        const float2 wt = *(const float2*)(wtmp + 2 * t);
        z0p = embt * wt.x;
        z1p = embt * wt.y;
    }
    for (int off = 32; off; off >>= 1) {
        z0p += __shfl_down(z0p, off, 64);
        z1p += __shfl_down(z1p, off, 64);
    }
    if (l == 0) { red0[w] = z0p; red1[w] = z1p; }
    __syncthreads();

    if (t == 0) {
        float z0 = bconst[0] + red0[0] + red0[1] + red0[2] + red0[3];
        float z1 = bconst[1] + red1[0] + red1[1] + red1[2] + red1[3];
        const float mz = fmaxf(z0, z1);
        const float e0 = expf(z0 - mz), e1 = expf(z1 - mz);
        const float inv = 1.0f / (e0 + e1);
        const float p0 = e0 * inv, p1 = e1 * inv;
        out[2 * g + 0] = p0;
        out[2 * g + 1] = p1;
        // loss term = -(log_softmax(probs)[label]) = lse(probs) - probs[label]
        const float mp  = fmaxf(p0, p1);
        const float lse = mp + logf(expf(p0 - mp) + expf(p1 - mp));
        lterm[g] = lse - ((label[g] == 0) ? p0 : p1);
        // release lterm[g], then signal done
        __threadfence();
        const int old = __hip_atomic_fetch_add(ws_i, 1, __ATOMIC_ACQ_REL,
                                               __HIP_MEMORY_SCOPE_AGENT);
        lastflag = (old == GG - 1);
    }
    __syncthreads();

    // ---- last finishing block: deterministic fixed-order loss sum ----
    if (lastflag) {
        __threadfence();   // acquire side: make other blocks' lterm visible
        if (t < 64) {
            const volatile float* lt = lterm;
            float v = lt[t] + lt[t + 64] + lt[t + 128] + lt[t + 192];
            for (int off = 32; off; off >>= 1) v += __shfl_down(v, off, 64);
            if (t == 0) out[2 * GG] = v;
        }
    }
}

extern "C" void kernel_launch(void* const* d_in, const int* in_sizes, int n_in,
                              void* d_out, int out_size, void* d_ws, size_t ws_size,
                              hipStream_t stream) {
    const float* node_fea  = (const float*)d_in[0];
    const float* masks     = (const float*)d_in[1];
    const int*   node_type = (const int*)  d_in[2];
    const int*   g_node_id = (const int*)  d_in[3];
    const int*   label     = (const int*)  d_in[4];
    const float* W_emb     = (const float*)d_in[5];
    const float* b_emb     = (const float*)d_in[6];
    const float* W_hid     = (const float*)d_in[7];
    const float* b_hid     = (const float*)d_in[8];
    const float* W_out     = (const float*)d_in[9];
    const float* b_out     = (const float*)d_in[10];

    float* out  = (float*)d_out;   // [G*2 probs][1 loss] = 513 floats
    float* ws_f = (float*)d_ws;
    int*   ws_i = (int*)d_ws;      // done-counter in bytes [0..3]

    wtmp_kernel<<<64, 256, 0, stream>>>(
        W_hid, b_hid, W_out, b_out, ws_f, ws_i);

    graph_kernel<<<GG, 256, 0, stream>>>(
        node_fea, masks, node_type, g_node_id, label,
        W_emb, b_emb, out, ws_f, ws_i);
}